// Round 9
// baseline (865.241 us; speedup 1.0000x reference)
//
#include <hip/hip_runtime.h>
#include <stdint.h>

typedef __attribute__((ext_vector_type(8))) short short8;
typedef __attribute__((ext_vector_type(4))) float f32x4;
typedef __attribute__((ext_vector_type(4))) int i32x4;

#define DMODEL 768
#define HID    2048
#define MROWS  4096   // 2*2048 tokens

// B-spline constants: h = (4-(-4))/(16-3) = 8/13
#define KINVH  (13.0f/8.0f)
#define KNOT0  (-4.0f - 3.0f*(8.0f/13.0f))

__device__ __forceinline__ unsigned short f2bf(float f) {
  unsigned int u = __float_as_uint(f);
  unsigned int r = (u + 0x7FFFu + ((u >> 16) & 1u)) >> 16;
  return (unsigned short)r;
}

// ---- weight f32 -> bf16 bits (4 elems/thread) ----
__global__ void __launch_bounds__(256) conv_bf16(const float* __restrict__ src,
                                                 unsigned short* __restrict__ dst,
                                                 int n4) {
  int i = blockIdx.x * 256 + threadIdx.x;
  if (i >= n4) return;
  float4 v = ((const float4*)src)[i];
  ushort4 o;
  o.x = f2bf(v.x); o.y = f2bf(v.y); o.z = f2bf(v.z); o.w = f2bf(v.w);
  ((ushort4*)dst)[i] = o;
}

// ---- split-K=2 reduce, in place: p[i] = p[i] + p[i+n4] ----
__global__ void __launch_bounds__(256) reduce2(float4* __restrict__ p, int n4) {
  int i = blockIdx.x * 256 + threadIdx.x;
  if (i >= n4) return;
  float4 a = p[i], b = p[i + n4];
  float4 r;
  r.x = a.x + b.x; r.y = a.y + b.y; r.z = a.z + b.z; r.w = a.w + b.w;
  p[i] = r;
}

// ---- split-K=4 reduce: out[i] = sum over 4 planes ----
__global__ void __launch_bounds__(256) reduce4(const float4* __restrict__ p,
                                               float4* __restrict__ out, int n4) {
  int i = blockIdx.x * 256 + threadIdx.x;
  if (i >= n4) return;
  float4 a = p[i], b = p[i + n4], c = p[i + 2 * n4], d = p[i + 3 * n4];
  float4 r;
  r.x = a.x + b.x + c.x + d.x;
  r.y = a.y + b.y + c.y + d.y;
  r.z = a.z + b.z + c.z + d.z;
  r.w = a.w + b.w + c.w + d.w;
  out[i] = r;
}

// ---- fused basis + GEMM, B-operand direct global->register ----
// C[n,o] = sum_{d,k} basis(X[n,d])_k * Wb[o, d*16+k]
// Tile: BM=64 x BN=256, BK=64. 4 waves in 1x4; wave tile 64x64 (FM=FN=4).
// B columns are wave-private -> B never touches LDS: each lane loads its
// MFMA B-fragment (16B contiguous: col=lane&15, k-block=lane>>4) straight
// from global, double-buffered in registers, next-step loads issued after
// the A-frag ds_reads so latency drains under the 32 MFMAs + barrier.
// Only the 8KB basis A-tile stages through LDS (swizzled scatter), with the
// plain 2-__syncthreads skeleton. LDS traffic/block-step: ~114KB -> ~44KB.
template<int DIN, int DOUT, int SPLITK>
__global__ void __launch_bounds__(256, 2)
kan_gemm(const float* __restrict__ X, const unsigned short* __restrict__ Wb,
         float* __restrict__ Out) {
  constexpr int BM  = 64;
  constexpr int BN  = 256;
  constexpr int NK  = (DIN * 16) / 64;
  constexpr int NKS = NK / SPLITK;
  constexpr int FM  = 4;
  constexpr int FN  = 4;
  __shared__ __align__(16) char smA[BM * 128];   // 64 rows x 64 bf16 (swizzled) = 8KB

  const int tid  = threadIdx.x;
  const int lane = tid & 63;
  const int wid  = tid >> 6;
  const int brow = blockIdx.x * BM;
  const int bcol = blockIdx.y * BN;
  const int kt0  = blockIdx.z * NKS;
  const int kt1  = kt0 + NKS;

  f32x4 acc[FM][FN];
#pragma unroll
  for (int m = 0; m < FM; ++m)
#pragma unroll
    for (int n = 0; n < FN; ++n) acc[m][n] = (f32x4){0.f, 0.f, 0.f, 0.f};

  // A-fragment LDS addressing (constant per lane)
  int a_base[FM], a_sw[FM];
#pragma unroll
  for (int m = 0; m < FM; ++m) {
    int row   = m * 16 + (lane & 15);
    a_base[m] = row * 128 + ((lane >> 4) * 16);
    a_sw[m]   = (row & 7) << 4;
  }

  // B-fragment global pointers: lane holds Wb[col][k-block] (16B contiguous)
  const unsigned short* bp[FN];
#pragma unroll
  for (int n = 0; n < FN; ++n)
    bp[n] = Wb + (size_t)(bcol + wid * 64 + n * 16 + (lane & 15)) * (DIN * 16)
               + (size_t)kt0 * 64 + (lane >> 4) * 8;

  const int br_ = tid >> 2;        // basis row
  const int bd_ = tid & 3;         // basis d-col within the 4-col step
  const float* xrow = X + (size_t)(brow + br_) * DIN + bd_;

  auto BASIS = [&](float xv) {
    float u  = (xv - KNOT0) * KINVH;
    float uf = floorf(u);
    int   jj = (int)uf;
    float t  = u - uf;
    float t2 = t * t, t3 = t2 * t;
    float p0 = (1.0f / 6.0f) * (1.0f - 3.0f * t + 3.0f * t2 - t3);
    float p1 = (1.0f / 6.0f) * (4.0f - 6.0f * t2 + 3.0f * t3);
    float p2 = (1.0f / 6.0f) * (1.0f + 3.0f * t + 3.0f * t2 - 3.0f * t3);
    float p3 = (1.0f / 6.0f) * t3;

    int base = br_ * 128 + bd_ * 32;
    int sw   = (br_ & 7) << 4;
    *(i32x4*)(smA + (base ^ sw))        = (i32x4){0, 0, 0, 0};
    *(i32x4*)(smA + ((base + 16) ^ sw)) = (i32x4){0, 0, 0, 0};
    unsigned short q0 = f2bf(p0), q1 = f2bf(p1), q2 = f2bf(p2), q3 = f2bf(p3);
    int k0 = jj - 3;
    if ((unsigned)(k0 + 0) < 16u) *(unsigned short*)(smA + ((base + (k0 + 0) * 2) ^ sw)) = q0;
    if ((unsigned)(k0 + 1) < 16u) *(unsigned short*)(smA + ((base + (k0 + 1) * 2) ^ sw)) = q1;
    if ((unsigned)(k0 + 2) < 16u) *(unsigned short*)(smA + ((base + (k0 + 2) * 2) ^ sw)) = q2;
    if ((unsigned)(k0 + 3) < 16u) *(unsigned short*)(smA + ((base + (k0 + 3) * 2) ^ sw)) = q3;
  };

  // ---- prologue: X(kt0) + B(kt0) in flight
  float xcur = xrow[(size_t)kt0 * 4];
  short8 bv0[FN], bv1[FN];
#pragma unroll
  for (int n = 0; n < FN; ++n) {
    bv0[n] = *(const short8*)(bp[n]);        // kk=0
    bv1[n] = *(const short8*)(bp[n] + 32);   // kk=1 (+64B)
  }

  for (int kt = kt0; kt < kt1; ++kt) {
    const bool more = (kt + 1 < kt1);
    __syncthreads();   // prev-step A-frag reads done; drains in-flight vmem

    BASIS(xcur);       // write this step's A-tile

    int ktn = more ? kt + 1 : kt;
    float xnext = xrow[(size_t)ktn * 4];   // consumed next iter (latency spans step)

    __syncthreads();   // A-tile visible

    // A fragments for both kk halves
    short8 a0[FM], a1[FM];
#pragma unroll
    for (int m = 0; m < FM; ++m) {
      a0[m] = *(const short8*)(smA + (a_base[m] ^ a_sw[m]));
      a1[m] = *(const short8*)(smA + ((a_base[m] + 64) ^ a_sw[m]));
    }

    // issue next-step B loads (drain at next iteration's barrier, hidden
    // under the 32 MFMAs below)
    short8 bn0[FN], bn1[FN];
    if (more) {
#pragma unroll
      for (int n = 0; n < FN; ++n) {
        bp[n] += 64;                            // advance one K-step (128B)
        bn0[n] = *(const short8*)(bp[n]);
        bn1[n] = *(const short8*)(bp[n] + 32);
      }
    }

#pragma unroll
    for (int m = 0; m < FM; ++m)
#pragma unroll
      for (int n = 0; n < FN; ++n)
        acc[m][n] = __builtin_amdgcn_mfma_f32_16x16x32_bf16(a0[m], bv0[n], acc[m][n], 0, 0, 0);
#pragma unroll
    for (int m = 0; m < FM; ++m)
#pragma unroll
      for (int n = 0; n < FN; ++n)
        acc[m][n] = __builtin_amdgcn_mfma_f32_16x16x32_bf16(a1[m], bv1[n], acc[m][n], 0, 0, 0);

    if (more) {
#pragma unroll
      for (int n = 0; n < FN; ++n) { bv0[n] = bn0[n]; bv1[n] = bn1[n]; }
    }
    xcur = xnext;
  }

  // ---- epilogue: C/D layout col=lane&15, row=(lane>>4)*4+q
  float* outp = Out + (size_t)blockIdx.z * MROWS * DOUT;
#pragma unroll
  for (int m = 0; m < FM; ++m)
#pragma unroll
    for (int n = 0; n < FN; ++n)
#pragma unroll
      for (int q = 0; q < 4; ++q) {
        int grow = brow + m * 16 + (lane >> 4) * 4 + q;
        int gcol = bcol + wid * 64 + n * 16 + (lane & 15);
        outp[(size_t)grow * DOUT + gcol] = acc[m][n][q];
      }
}

extern "C" void kernel_launch(void* const* d_in, const int* in_sizes, int n_in,
                              void* d_out, int out_size, void* d_ws, size_t ws_size,
                              hipStream_t stream) {
  const float* x  = (const float*)d_in[0];   // (2,2048,768) f32 -> (4096,768)
  const float* w1 = (const float*)d_in[1];   // (2048,768,16) f32
  const float* w2 = (const float*)d_in[2];   // (768,2048,16) f32
  float* out = (float*)d_out;                // (4096,768) f32

  // ws timeline (128 MiB):
  //   [0, 48M)   : w1b (phase 1), then w2b (phase 2, after GEMM1)
  //   [48M, 80M) : GEMM1 partial plane 0 -> becomes h (f32) after reduce2
  //   [80M, 112M): GEMM1 partial plane 1 (dead after reduce2)
  //   [80M, 128M): GEMM2 partial planes 0..3 (overwrites plane 1)
  char* ws = (char*)d_ws;
  unsigned short* wgb   = (unsigned short*)ws;                  // 50,331,648 B
  float*          part1 = (float*)(ws + 50331648);              // 2 x 33,554,432 B
  float*          hbf   = part1;                                // alias: plane 0
  float*          part2 = (float*)(ws + 83886080);              // 4 x 12,582,912 B (end = 128MiB)

  const int n4 = (HID * DMODEL * 16) / 4;    // 6,291,456 float4 groups per weight

  // phase 1: layer 1
  conv_bf16<<<n4 / 256, 256, 0, stream>>>(w1, wgb, n4);
  kan_gemm<DMODEL, HID, 2>
      <<<dim3(MROWS / 64, HID / 256, 2), 256, 0, stream>>>(x, wgb, part1);
  const int hn4 = (MROWS * HID) / 4;         // 2,097,152
  reduce2<<<hn4 / 256, 256, 0, stream>>>((float4*)part1, hn4);   // h = plane0

  // phase 2: layer 2 (convert w2 now that w1b is dead)
  conv_bf16<<<n4 / 256, 256, 0, stream>>>(w2, wgb, n4);
  kan_gemm<HID, DMODEL, 4>
      <<<dim3(MROWS / 64, DMODEL / 256, 4), 256, 0, stream>>>(hbf, wgb, part2);
  const int rn4 = (MROWS * DMODEL) / 4;      // 786,432
  reduce4<<<rn4 / 256, 256, 0, stream>>>((const float4*)part2, (float4*)out, rn4);
}

// Round 10
// 644.624 us; speedup vs baseline: 1.3422x; 1.3422x over previous
//
#include <hip/hip_runtime.h>
#include <stdint.h>

typedef __attribute__((ext_vector_type(8))) short short8;
typedef __attribute__((ext_vector_type(4))) float f32x4;
typedef __attribute__((ext_vector_type(16))) float f32x16;
typedef __attribute__((ext_vector_type(4))) int i32x4;

#define DMODEL 768
#define HID    2048
#define MROWS  4096   // 2*2048 tokens

// B-spline constants: h = (4-(-4))/(16-3) = 8/13
#define KINVH  (13.0f/8.0f)
#define KNOT0  (-4.0f - 3.0f*(8.0f/13.0f))

__device__ __forceinline__ unsigned short f2bf(float f) {
  unsigned int u = __float_as_uint(f);
  unsigned int r = (u + 0x7FFFu + ((u >> 16) & 1u)) >> 16;
  return (unsigned short)r;
}

// ---- weight f32 -> bf16 bits (4 elems/thread) ----
__global__ void __launch_bounds__(256) conv_bf16(const float* __restrict__ src,
                                                 unsigned short* __restrict__ dst,
                                                 int n4) {
  int i = blockIdx.x * 256 + threadIdx.x;
  if (i >= n4) return;
  float4 v = ((const float4*)src)[i];
  ushort4 o;
  o.x = f2bf(v.x); o.y = f2bf(v.y); o.z = f2bf(v.z); o.w = f2bf(v.w);
  ((ushort4*)dst)[i] = o;
}

// ---- split-K=2 reduce, in place: p[i] = p[i] + p[i+n4] ----
__global__ void __launch_bounds__(256) reduce2(float4* __restrict__ p, int n4) {
  int i = blockIdx.x * 256 + threadIdx.x;
  if (i >= n4) return;
  float4 a = p[i], b = p[i + n4];
  float4 r;
  r.x = a.x + b.x; r.y = a.y + b.y; r.z = a.z + b.z; r.w = a.w + b.w;
  p[i] = r;
}

// ---- split-K=4 reduce: out[i] = sum over 4 planes ----
__global__ void __launch_bounds__(256) reduce4(const float4* __restrict__ p,
                                               float4* __restrict__ out, int n4) {
  int i = blockIdx.x * 256 + threadIdx.x;
  if (i >= n4) return;
  float4 a = p[i], b = p[i + n4], c = p[i + 2 * n4], d = p[i + 3 * n4];
  float4 r;
  r.x = a.x + b.x + c.x + d.x;
  r.y = a.y + b.y + c.y + d.y;
  r.z = a.z + b.z + c.z + d.z;
  r.w = a.w + b.w + c.w + d.w;
  out[i] = r;
}

// ---- fused basis + GEMM (r7 2-barrier skeleton + 32x32x16 MFMA + XCD swizzle) ----
// C[n,o] = sum_{d,k} basis(X[n,d])_k * Wb[o, d*16+k]
// Tile: BM=64 x BN=256, BK=64. 4 waves in 1x4; wave tile 64x64:
// FM=FN=2 frags of 32, 4 k-slices of 16 -> 16 v_mfma_f32_32x32x16_bf16/step
// (vs 32 16x16x32: ~20% less matrix-pipe issue, half the inner-loop insts).
// A/B operand map: row|col = lane&31, k = (lane>>5)*8 + i (16B contiguous).
// C/D map: col = lane&31, row = (r&3) + 8*(r>>2) + 4*(lane>>5)  [m74/m101].
// XCD swizzle: dispatch d=(x + y*gx) -> logical lf=(d&7)*cpx + (d>>3)
// (nwg%8==0, bijective) so one XCD owns a whole y-strip: B-panel L2-resident.
template<int DIN, int DOUT, int SPLITK>
__global__ void __launch_bounds__(256, 2)
kan_gemm(const float* __restrict__ X, const unsigned short* __restrict__ Wb,
         float* __restrict__ Out) {
  constexpr int BM  = 64;
  constexpr int BN  = 256;
  constexpr int NK  = (DIN * 16) / 64;
  constexpr int NKS = NK / SPLITK;
  constexpr int GX  = MROWS / BM;          // 64
  constexpr int GY  = DOUT / BN;
  constexpr int CPX = (GX * GY) / 8;       // blocks per XCD
  __shared__ __align__(16) char smA[BM * 128];   // 64 rows x 64 bf16 (swizzled) = 8KB
  __shared__ __align__(16) char smB[BN * 128];   // 256 rows x 64 bf16 (swizzled via source) = 32KB

  const int tid  = threadIdx.x;
  const int lane = tid & 63;
  const int wid  = tid >> 6;

  // XCD-chunked remap of (x,y)
  const int d  = blockIdx.x + blockIdx.y * GX;
  const int lf = (d & 7) * CPX + (d >> 3);
  const int brow = (lf % GX) * BM;
  const int bcol = (lf / GX) * BN;
  const int kt0  = blockIdx.z * NKS;
  const int kt1  = kt0 + NKS;

  f32x16 acc[2][2];
#pragma unroll
  for (int m = 0; m < 2; ++m)
#pragma unroll
    for (int n = 0; n < 2; ++n)
#pragma unroll
      for (int q = 0; q < 16; ++q) acc[m][n][q] = 0.f;

  // fragment LDS addressing (constant per lane; k-slice added in-loop)
  int a_base[2], a_sw[2], b_base[2], b_sw[2];
#pragma unroll
  for (int m = 0; m < 2; ++m) {
    int row   = m * 32 + (lane & 31);
    a_base[m] = row * 128 + ((lane >> 5) * 16);
    a_sw[m]   = (row & 7) << 4;
  }
#pragma unroll
  for (int n = 0; n < 2; ++n) {
    int row   = wid * 64 + n * 32 + (lane & 31);
    b_base[n] = row * 128 + ((lane >> 5) * 16);
    b_sw[n]   = (row & 7) << 4;
  }

  const int br_ = tid >> 2;        // basis row
  const int bd_ = tid & 3;         // basis d-col within the 4-col step
  const float* xrow = X + (size_t)(brow + br_) * DIN + bd_;

  // prologue: prefetch X for kt0
  float xcur = xrow[(size_t)kt0 * 4];

  for (int kt = kt0; kt < kt1; ++kt) {
    __syncthreads();   // previous compute done before overwriting LDS

    // ---- stage B: 32KB via global_load_lds width-16, pre-swizzled source.
#pragma unroll
    for (int i = 0; i < 8; ++i) {
      const int c   = wid * 8 + i;              // wave-uniform chunk (8 rows = 1KB)
      const int row = c * 8 + (lane >> 3);
      const int gch = (lane & 7) ^ (lane >> 3);
      const unsigned short* src =
          Wb + (size_t)(bcol + row) * (DIN * 16) + kt * 64 + gch * 8;
      __builtin_amdgcn_global_load_lds(
          (const __attribute__((address_space(1))) unsigned int*)src,
          (__attribute__((address_space(3))) unsigned int*)(smB + c * 1024),
          16, 0, 0);
    }

    // ---- stage A: basis from prefetched xcur, scatter to swizzled LDS
    {
      float u  = (xcur - KNOT0) * KINVH;
      float uf = floorf(u);
      int   jj = (int)uf;
      float t  = u - uf;
      float t2 = t * t, t3 = t2 * t;
      float p0 = (1.0f / 6.0f) * (1.0f - 3.0f * t + 3.0f * t2 - t3);
      float p1 = (1.0f / 6.0f) * (4.0f - 6.0f * t2 + 3.0f * t3);
      float p2 = (1.0f / 6.0f) * (1.0f + 3.0f * t + 3.0f * t2 - 3.0f * t3);
      float p3 = (1.0f / 6.0f) * t3;

      int base = br_ * 128 + bd_ * 32;
      int sw   = (br_ & 7) << 4;
      *(i32x4*)(smA + (base ^ sw))        = (i32x4){0, 0, 0, 0};
      *(i32x4*)(smA + ((base + 16) ^ sw)) = (i32x4){0, 0, 0, 0};
      unsigned short q0 = f2bf(p0), q1 = f2bf(p1), q2 = f2bf(p2), q3 = f2bf(p3);
      int k0 = jj - 3;
      if ((unsigned)(k0 + 0) < 16u) *(unsigned short*)(smA + ((base + (k0 + 0) * 2) ^ sw)) = q0;
      if ((unsigned)(k0 + 1) < 16u) *(unsigned short*)(smA + ((base + (k0 + 1) * 2) ^ sw)) = q1;
      if ((unsigned)(k0 + 2) < 16u) *(unsigned short*)(smA + ((base + (k0 + 2) * 2) ^ sw)) = q2;
      if ((unsigned)(k0 + 3) < 16u) *(unsigned short*)(smA + ((base + (k0 + 3) * 2) ^ sw)) = q3;
    }

    // ---- prefetch X for next step (latency drains under the same barrier as B)
    {
      int ktn = (kt + 1 < kt1) ? kt + 1 : kt;
      xcur = xrow[(size_t)ktn * 4];   // note: used NEXT iteration
      // keep this iteration's value alive separately below
    }

    __syncthreads();   // drains LDS writes AND vmem (B tile + X prefetch)

    // ---- compute: 4 k-slices of 16
#pragma unroll
    for (int ks = 0; ks < 4; ++ks) {
      short8 av[2], bv[2];
#pragma unroll
      for (int m = 0; m < 2; ++m)
        av[m] = *(const short8*)(smA + ((a_base[m] + ks * 32) ^ a_sw[m]));
#pragma unroll
      for (int n = 0; n < 2; ++n)
        bv[n] = *(const short8*)(smB + ((b_base[n] + ks * 32) ^ b_sw[n]));
#pragma unroll
      for (int m = 0; m < 2; ++m)
#pragma unroll
        for (int n = 0; n < 2; ++n)
          acc[m][n] = __builtin_amdgcn_mfma_f32_32x32x16_bf16(av[m], bv[n], acc[m][n], 0, 0, 0);
    }
  }

  // ---- epilogue: C/D layout col=lane&31, row=(r&3)+8*(r>>2)+4*(lane>>5)
  float* outp = Out + (size_t)blockIdx.z * MROWS * DOUT;
#pragma unroll
  for (int m = 0; m < 2; ++m)
#pragma unroll
    for (int n = 0; n < 2; ++n)
#pragma unroll
      for (int r = 0; r < 16; ++r) {
        int grow = brow + m * 32 + (r & 3) + 8 * (r >> 2) + 4 * (lane >> 5);
        int gcol = bcol + wid * 64 + n * 32 + (lane & 31);
        outp[(size_t)grow * DOUT + gcol] = acc[m][n][r];
      }
}

extern "C" void kernel_launch(void* const* d_in, const int* in_sizes, int n_in,
                              void* d_out, int out_size, void* d_ws, size_t ws_size,
                              hipStream_t stream) {
  const float* x  = (const float*)d_in[0];   // (2,2048,768) f32 -> (4096,768)
  const float* w1 = (const float*)d_in[1];   // (2048,768,16) f32
  const float* w2 = (const float*)d_in[2];   // (768,2048,16) f32
  float* out = (float*)d_out;                // (4096,768) f32

  // ws timeline (128 MiB):
  //   [0, 48M)   : w1b (phase 1), then w2b (phase 2, after GEMM1)
  //   [48M, 80M) : GEMM1 partial plane 0 -> becomes h (f32) after reduce2
  //   [80M, 112M): GEMM1 partial plane 1 (dead after reduce2)
  //   [80M, 128M): GEMM2 partial planes 0..3 (overwrites plane 1)
  char* ws = (char*)d_ws;
  unsigned short* wgb   = (unsigned short*)ws;                  // 50,331,648 B
  float*          part1 = (float*)(ws + 50331648);              // 2 x 33,554,432 B
  float*          hbf   = part1;                                // alias: plane 0
  float*          part2 = (float*)(ws + 83886080);              // 4 x 12,582,912 B (end = 128MiB)

  const int n4 = (HID * DMODEL * 16) / 4;    // 6,291,456 float4 groups per weight

  // phase 1: layer 1
  conv_bf16<<<n4 / 256, 256, 0, stream>>>(w1, wgb, n4);
  kan_gemm<DMODEL, HID, 2>
      <<<dim3(MROWS / 64, HID / 256, 2), 256, 0, stream>>>(x, wgb, part1);
  const int hn4 = (MROWS * HID) / 4;         // 2,097,152
  reduce2<<<hn4 / 256, 256, 0, stream>>>((float4*)part1, hn4);   // h = plane0

  // phase 2: layer 2 (convert w2 now that w1b is dead)
  conv_bf16<<<n4 / 256, 256, 0, stream>>>(w2, wgb, n4);
  kan_gemm<HID, DMODEL, 4>
      <<<dim3(MROWS / 64, DMODEL / 256, 4), 256, 0, stream>>>(hbf, wgb, part2);
  const int rn4 = (MROWS * DMODEL) / 4;      // 786,432
  reduce4<<<rn4 / 256, 256, 0, stream>>>((const float4*)part2, (float4*)out, rn4);
}

// Round 11
// 510.018 us; speedup vs baseline: 1.6965x; 1.2639x over previous
//
#include <hip/hip_runtime.h>
#include <stdint.h>

typedef __attribute__((ext_vector_type(8))) short short8;
typedef __attribute__((ext_vector_type(4))) float f32x4;
typedef __attribute__((ext_vector_type(4))) int i32x4;

#define DMODEL 768
#define HID    2048
#define MROWS  4096   // 2*2048 tokens

// B-spline constants: h = (4-(-4))/(16-3) = 8/13
#define KINVH  (13.0f/8.0f)
#define KNOT0  (-4.0f - 3.0f*(8.0f/13.0f))

__device__ __forceinline__ unsigned short f2bf(float f) {
  unsigned int u = __float_as_uint(f);
  unsigned int r = (u + 0x7FFFu + ((u >> 16) & 1u)) >> 16;
  return (unsigned short)r;
}

// ---- weight f32 -> bf16, packed in MFMA-fragment order ----
// src: w[O][DIN][16] f32.  dst 16B-unit layout: [cb=col/16][kt2=k/32][q=l>>4][c16=l&15],
// unit content = 8 bf16 at k = kt2*32 + q*8 .. +8 of column cb*16+c16.
// A B-fragment load (fixed cb,kt2) is then lane-linear: addr = base + lane*16B.
// One wave per (cb, kt2): reads 128B contiguous per column, writes one 1KB coalesced block.
template<int DIN>
__global__ void __launch_bounds__(256) conv_pack(const float* __restrict__ src,
                                                 unsigned short* __restrict__ dst,
                                                 int total_waves) {
  constexpr int NK2 = DIN / 2;               // number of 32-wide k halves
  int gw = blockIdx.x * 4 + (threadIdx.x >> 6);
  if (gw >= total_waves) return;
  int l   = threadIdx.x & 63;
  int cb  = gw / NK2;
  int kt2 = gw % NK2;
  int c16 = l & 15, q = l >> 4;
  int col = cb * 16 + c16;
  const float* s = src + ((size_t)col * DIN + kt2 * 2 + (q >> 1)) * 16 + (q & 1) * 8;
  float4 v0 = *(const float4*)s;
  float4 v1 = *(const float4*)(s + 4);
  short8 o;
  o[0] = (short)f2bf(v0.x); o[1] = (short)f2bf(v0.y);
  o[2] = (short)f2bf(v0.z); o[3] = (short)f2bf(v0.w);
  o[4] = (short)f2bf(v1.x); o[5] = (short)f2bf(v1.y);
  o[6] = (short)f2bf(v1.z); o[7] = (short)f2bf(v1.w);
  unsigned short* d = dst + (((size_t)cb * NK2 + kt2) * 64 + q * 16 + c16) * 8;
  *(short8*)d = o;
}

// ---- split-K=2 reduce, in place: p[i] = p[i] + p[i+n4] ----
__global__ void __launch_bounds__(256) reduce2(float4* __restrict__ p, int n4) {
  int i = blockIdx.x * 256 + threadIdx.x;
  if (i >= n4) return;
  float4 a = p[i], b = p[i + n4];
  float4 r;
  r.x = a.x + b.x; r.y = a.y + b.y; r.z = a.z + b.z; r.w = a.w + b.w;
  p[i] = r;
}

// ---- split-K=4 reduce: out[i] = sum over 4 planes ----
__global__ void __launch_bounds__(256) reduce4(const float4* __restrict__ p,
                                               float4* __restrict__ out, int n4) {
  int i = blockIdx.x * 256 + threadIdx.x;
  if (i >= n4) return;
  float4 a = p[i], b = p[i + n4], c = p[i + 2 * n4], d = p[i + 3 * n4];
  float4 r;
  r.x = a.x + b.x + c.x + d.x;
  r.y = a.y + b.y + c.y + d.y;
  r.z = a.z + b.z + c.z + d.z;
  r.w = a.w + b.w + c.w + d.w;
  out[i] = r;
}

// ---- fused basis + GEMM: A via LDS (8KB), B direct global->register ----
// C[n,o] = sum_{d,k} basis(X[n,d])_k * Wb'[o,k]
// Tile: BM=64 x BN=256, BK=64. 4 waves in 1x4; wave tile 64x64 (FM=FN=4, 16x16x32).
// B fragments load straight from the pre-packed Wb' (one coalesced 1KB wave-load
// each, L2-served, XCD-swizzled for reuse) -> B-staging writes AND B ds_reads
// eliminated: LDS traffic/block-step 106KB -> 42KB (the r7 saturated pipe).
// Next-step B loads issue after this step's MFMAs (~400cy lead to barrier drain).
template<int DIN, int DOUT, int SPLITK>
__global__ void __launch_bounds__(256, 2)
kan_gemm(const float* __restrict__ X, const unsigned short* __restrict__ Wb,
         float* __restrict__ Out) {
  constexpr int BM  = 64;
  constexpr int BN  = 256;
  constexpr int NK  = (DIN * 16) / 64;
  constexpr int NK2 = DIN / 2;
  constexpr int NKS = NK / SPLITK;
  constexpr int GX  = MROWS / BM;          // 64
  constexpr int GY  = DOUT / BN;
  constexpr int CPX = (GX * GY) / 8;       // blocks per XCD (nwg%8==0, bijective)
  __shared__ __align__(16) char smA[BM * 128];   // 64 rows x 64 bf16 (swizzled) = 8KB

  const int tid  = threadIdx.x;
  const int lane = tid & 63;
  const int wid  = tid >> 6;

  // XCD-chunked remap: each XCD gets a contiguous lf strip (brow sweeps, bcol ~fixed)
  const int d    = blockIdx.x + blockIdx.y * GX;
  const int lf   = (d & 7) * CPX + (d >> 3);
  const int brow = (lf % GX) * BM;
  const int bcol = (lf / GX) * BN;
  const int kt0  = blockIdx.z * NKS;
  const int kt1  = kt0 + NKS;

  f32x4 acc[4][4];
#pragma unroll
  for (int m = 0; m < 4; ++m)
#pragma unroll
    for (int n = 0; n < 4; ++n) acc[m][n] = (f32x4){0.f, 0.f, 0.f, 0.f};

  // A-fragment LDS addressing (constant per lane)
  int a_base[4], a_sw[4];
#pragma unroll
  for (int m = 0; m < 4; ++m) {
    int row   = m * 16 + (lane & 15);
    a_base[m] = row * 128 + ((lane >> 4) * 16);
    a_sw[m]   = (row & 7) << 4;
  }

  // B-fragment pointers: frag n, lane-linear in packed layout
  const unsigned short* bp[4];
#pragma unroll
  for (int n = 0; n < 4; ++n)
    bp[n] = Wb + ((size_t)(bcol / 16 + wid * 4 + n) * NK2 + (size_t)kt0 * 2) * 512
               + lane * 8;

  const int br_ = tid >> 2;        // basis row
  const int bd_ = tid & 3;         // basis d-col within the 4-col step
  const float* xrow = X + (size_t)(brow + br_) * DIN + bd_;

  // ---- prologue: X(kt0) + B(kt0) in flight
  float xcur = xrow[(size_t)kt0 * 4];
  short8 bv[2][4];
#pragma unroll
  for (int n = 0; n < 4; ++n) {
    bv[0][n] = *(const short8*)(bp[n]);
    bv[1][n] = *(const short8*)(bp[n] + 512);
    bp[n] += 1024;
  }

  for (int kt = kt0; kt < kt1; ++kt) {
    __syncthreads();   // prev A-frag reads done; drains in-flight vmem (B/X landed)

    // ---- stage A: basis from prefetched xcur, scatter to swizzled LDS
    {
      float u  = (xcur - KNOT0) * KINVH;
      float uf = floorf(u);
      int   jj = (int)uf;
      float t  = u - uf;
      float t2 = t * t, t3 = t2 * t;
      float p0 = (1.0f / 6.0f) * (1.0f - 3.0f * t + 3.0f * t2 - t3);
      float p1 = (1.0f / 6.0f) * (4.0f - 6.0f * t2 + 3.0f * t3);
      float p2 = (1.0f / 6.0f) * (1.0f + 3.0f * t + 3.0f * t2 - 3.0f * t3);
      float p3 = (1.0f / 6.0f) * t3;

      int base = br_ * 128 + bd_ * 32;
      int sw   = (br_ & 7) << 4;
      *(i32x4*)(smA + (base ^ sw))        = (i32x4){0, 0, 0, 0};
      *(i32x4*)(smA + ((base + 16) ^ sw)) = (i32x4){0, 0, 0, 0};
      unsigned short q0 = f2bf(p0), q1 = f2bf(p1), q2 = f2bf(p2), q3 = f2bf(p3);
      int k0 = jj - 3;
      if ((unsigned)(k0 + 0) < 16u) *(unsigned short*)(smA + ((base + (k0 + 0) * 2) ^ sw)) = q0;
      if ((unsigned)(k0 + 1) < 16u) *(unsigned short*)(smA + ((base + (k0 + 1) * 2) ^ sw)) = q1;
      if ((unsigned)(k0 + 2) < 16u) *(unsigned short*)(smA + ((base + (k0 + 2) * 2) ^ sw)) = q2;
      if ((unsigned)(k0 + 3) < 16u) *(unsigned short*)(smA + ((base + (k0 + 3) * 2) ^ sw)) = q3;
    }

    // prefetch X for next step
    {
      int ktn = (kt + 1 < kt1) ? kt + 1 : kt;
      xcur = xrow[(size_t)ktn * 4];
    }

    __syncthreads();   // A-tile visible

    // A fragments for both kk halves (8 ds_read_b128, 2-way conflict = free)
    short8 a0[4], a1[4];
#pragma unroll
    for (int m = 0; m < 4; ++m) {
      a0[m] = *(const short8*)(smA + (a_base[m] ^ a_sw[m]));
      a1[m] = *(const short8*)(smA + ((a_base[m] + 64) ^ a_sw[m]));
    }

    // MFMA on current B registers
#pragma unroll
    for (int m = 0; m < 4; ++m)
#pragma unroll
      for (int n = 0; n < 4; ++n)
        acc[m][n] = __builtin_amdgcn_mfma_f32_16x16x32_bf16(a0[m], bv[0][n], acc[m][n], 0, 0, 0);
#pragma unroll
    for (int m = 0; m < 4; ++m)
#pragma unroll
      for (int n = 0; n < 4; ++n)
        acc[m][n] = __builtin_amdgcn_mfma_f32_16x16x32_bf16(a1[m], bv[1][n], acc[m][n], 0, 0, 0);

    // issue next-step B loads into bv (WAR after MFMAs; drain at next barrier)
    if (kt + 1 < kt1) {
#pragma unroll
      for (int n = 0; n < 4; ++n) {
        bv[0][n] = *(const short8*)(bp[n]);
        bv[1][n] = *(const short8*)(bp[n] + 512);
        bp[n] += 1024;
      }
    }
  }

  // ---- epilogue: C/D layout col=lane&15, row=(lane>>4)*4+q
  float* outp = Out + (size_t)blockIdx.z * MROWS * DOUT;
#pragma unroll
  for (int m = 0; m < 4; ++m)
#pragma unroll
    for (int n = 0; n < 4; ++n)
#pragma unroll
      for (int q = 0; q < 4; ++q) {
        int grow = brow + m * 16 + (lane >> 4) * 4 + q;
        int gcol = bcol + wid * 64 + n * 16 + (lane & 15);
        outp[(size_t)grow * DOUT + gcol] = acc[m][n][q];
      }
}

extern "C" void kernel_launch(void* const* d_in, const int* in_sizes, int n_in,
                              void* d_out, int out_size, void* d_ws, size_t ws_size,
                              hipStream_t stream) {
  const float* x  = (const float*)d_in[0];   // (2,2048,768) f32 -> (4096,768)
  const float* w1 = (const float*)d_in[1];   // (2048,768,16) f32
  const float* w2 = (const float*)d_in[2];   // (768,2048,16) f32
  float* out = (float*)d_out;                // (4096,768) f32

  // ws timeline (128 MiB):
  //   [0, 48M)   : w1b' (phase 1), then w2b' (phase 2, after GEMM1)
  //   [48M, 80M) : GEMM1 partial plane 0 -> becomes h (f32) after reduce2
  //   [80M, 112M): GEMM1 partial plane 1 (dead after reduce2)
  //   [80M, 128M): GEMM2 partial planes 0..3 (overwrites plane 1)
  char* ws = (char*)d_ws;
  unsigned short* wgb   = (unsigned short*)ws;                  // 50,331,648 B
  float*          part1 = (float*)(ws + 50331648);              // 2 x 33,554,432 B
  float*          hbf   = part1;                                // alias: plane 0
  float*          part2 = (float*)(ws + 83886080);              // 4 x 12,582,912 B (end = 128MiB)

  // phase 1: layer 1
  {
    const int waves = (HID / 16) * (DMODEL / 2);   // 128 * 384 = 49152
    conv_pack<DMODEL><<<waves / 4, 256, 0, stream>>>(w1, wgb, waves);
  }
  kan_gemm<DMODEL, HID, 2>
      <<<dim3(MROWS / 64, HID / 256, 2), 256, 0, stream>>>(x, wgb, part1);
  const int hn4 = (MROWS * HID) / 4;         // 2,097,152
  reduce2<<<hn4 / 256, 256, 0, stream>>>((float4*)part1, hn4);   // h = plane0

  // phase 2: layer 2 (pack w2 now that w1b' is dead)
  {
    const int waves = (DMODEL / 16) * (HID / 2);   // 48 * 1024 = 49152
    conv_pack<HID><<<waves / 4, 256, 0, stream>>>(w2, wgb, waves);
  }
  kan_gemm<HID, DMODEL, 4>
      <<<dim3(MROWS / 64, DMODEL / 256, 4), 256, 0, stream>>>(hbf, wgb, part2);
  const int rn4 = (MROWS * DMODEL) / 4;      // 786,432
  reduce4<<<rn4 / 256, 256, 0, stream>>>((const float4*)part2, (float4*)out, rn4);
}